// Round 1
// baseline (537.269 us; speedup 1.0000x reference)
//
#include <hip/hip_runtime.h>
#include <math.h>

#define BB 8192
#define XD 784
#define ZD 10
#define KK 2000
#define HH 300
#define NSPLIT 8

__device__ __forceinline__ float sp_(float x) {
    return fmaxf(x, 0.f) + log1pf(expf(-fabsf(x)));
}
__device__ __forceinline__ float elu_(float x) {
    return x > 0.f ? x : expm1f(x);
}

// Generic tiled fp32 GEMM: C[M,N] = act(A[M,K] @ W[K,N] + bias)
// MODE 0: store raw, MODE 1: store elu, MODE 2: don't store C; accumulate
// per-row partial of sum_cols( X*logit - softplus(logit) ) into lpx_part.
template<int MODE>
__global__ __launch_bounds__(256)
void gemm_k(const float* __restrict__ A, const float* __restrict__ W,
            const float* __restrict__ bias, float* __restrict__ C,
            const float* __restrict__ X, float* __restrict__ lpx_part,
            int M, int N, int Kd)
{
    __shared__ __align__(16) float As[16][68];
    __shared__ __align__(16) float Bs[16][68];
    const int tid = threadIdx.x;
    const int tx = tid & 15, ty = tid >> 4;
    const int n0 = blockIdx.x * 64, m0 = blockIdx.y * 64;
    const int arow = tid >> 2, acol = (tid & 3) * 4;
    const int brow = tid >> 4, bcol = (tid & 15) * 4;
    float acc[4][4] = {};

    for (int kt = 0; kt < Kd; kt += 16) {
        #pragma unroll
        for (int i = 0; i < 4; ++i) {
            int k = kt + acol + i;
            int r = m0 + arow;
            As[acol + i][arow] = (k < Kd && r < M) ? A[(size_t)r * Kd + k] : 0.f;
        }
        #pragma unroll
        for (int i = 0; i < 4; ++i) {
            int k = kt + brow;
            int c = n0 + bcol + i;
            Bs[brow][bcol + i] = (k < Kd && c < N) ? W[(size_t)k * N + c] : 0.f;
        }
        __syncthreads();
        #pragma unroll
        for (int kk = 0; kk < 16; ++kk) {
            float4 av = *reinterpret_cast<const float4*>(&As[kk][ty * 4]);
            float4 bv = *reinterpret_cast<const float4*>(&Bs[kk][tx * 4]);
            float a[4] = {av.x, av.y, av.z, av.w};
            float b[4] = {bv.x, bv.y, bv.z, bv.w};
            #pragma unroll
            for (int i = 0; i < 4; ++i)
                #pragma unroll
                for (int j = 0; j < 4; ++j)
                    acc[i][j] = fmaf(a[i], b[j], acc[i][j]);
        }
        __syncthreads();
    }

    if (MODE == 2) {
        float rowsum[4] = {0.f, 0.f, 0.f, 0.f};
        #pragma unroll
        for (int i = 0; i < 4; ++i) {
            int r = m0 + ty * 4 + i;
            #pragma unroll
            for (int j = 0; j < 4; ++j) {
                int c = n0 + tx * 4 + j;
                if (r < M && c < N) {
                    float l = acc[i][j] + bias[c];
                    float xv = X[(size_t)r * N + c];
                    rowsum[i] += xv * l - sp_(l);
                }
            }
        }
        __shared__ float red[64][17];
        #pragma unroll
        for (int i = 0; i < 4; ++i) red[ty * 4 + i][tx] = rowsum[i];
        __syncthreads();
        if (tid < 64 && m0 + tid < M) {
            float s = 0.f;
            #pragma unroll
            for (int t = 0; t < 16; ++t) s += red[tid][t];
            lpx_part[(size_t)blockIdx.x * M + m0 + tid] = s;
        }
    } else {
        #pragma unroll
        for (int i = 0; i < 4; ++i) {
            int r = m0 + ty * 4 + i;
            if (r >= M) continue;
            #pragma unroll
            for (int j = 0; j < 4; ++j) {
                int c = n0 + tx * 4 + j;
                if (c < N) {
                    float v = acc[i][j] + bias[c];
                    if (MODE == 1) v = elu_(v);
                    C[(size_t)r * N + c] = v;
                }
            }
        }
    }
}

// h3[B,20] -> qm/qv -> z, log_qz
__global__ __launch_bounds__(256)
void reparam_k(const float* __restrict__ h3, const float* __restrict__ eps,
               float* __restrict__ z, float* __restrict__ lqz)
{
    int r = blockIdx.x * blockDim.x + threadIdx.x;
    if (r >= BB) return;
    float acc = 0.f;
    #pragma unroll
    for (int j = 0; j < ZD; ++j) {
        float qm = h3[r * 2 * ZD + j];
        float qh = h3[r * 2 * ZD + ZD + j];
        float qv = sp_(qh) + 1e-8f;
        float e  = eps[r * ZD + j];
        float zj = qm + sqrtf(qv) * e;
        z[r * ZD + j] = zj;
        float d = zj - qm;
        acc += logf(6.283185307179586f * qv) + d * d / qv;
    }
    lqz[r] = -0.5f * acc;
}

// GMM prior -> 21 SoA coefficients per component:
// comp[b,k] = c_k + sum_j z^2 * (-0.5/v) + sum_j z * (m/v)
__global__ __launch_bounds__(256)
void coef_k(const float* __restrict__ zpre, float* __restrict__ coef)
{
    int k = blockIdx.x * blockDim.x + threadIdx.x;
    if (k >= KK) return;
    float csum = 0.f;
    #pragma unroll
    for (int j = 0; j < ZD; ++j) {
        float m = zpre[k * ZD + j];
        float h = zpre[(KK + k) * ZD + j];
        float v = sp_(h) + 1e-8f;
        coef[j * KK + k]        = -0.5f / v;
        coef[(ZD + j) * KK + k] = m / v;
        csum += logf(6.283185307179586f * v) + m * m / v;
    }
    coef[2 * ZD * KK + k] = -0.5f * csum;
}

// one thread per row, online logsumexp over a K/NSPLIT chunk.
// k is block-uniform -> coef reads compile to scalar loads.
__global__ __launch_bounds__(256)
void comp_k(const float* __restrict__ z, const float* __restrict__ coef,
            float* __restrict__ pm, float* __restrict__ ps)
{
    int r = blockIdx.x * 256 + threadIdx.x;
    float zr[ZD], f2[ZD];
    #pragma unroll
    for (int j = 0; j < ZD; ++j) {
        zr[j] = z[r * ZD + j];
        f2[j] = zr[j] * zr[j];
    }
    int kb = blockIdx.y * (KK / NSPLIT);
    int ke = kb + KK / NSPLIT;
    float m = -1e30f, s = 0.f;
    for (int k = kb; k < ke; ++k) {
        float c = coef[2 * ZD * KK + k];
        #pragma unroll
        for (int j = 0; j < ZD; ++j) c = fmaf(f2[j], coef[j * KK + k], c);
        #pragma unroll
        for (int j = 0; j < ZD; ++j) c = fmaf(zr[j], coef[(ZD + j) * KK + k], c);
        if (c > m) { s = s * expf(m - c) + 1.f; m = c; }
        else       { s += expf(c - m); }
    }
    pm[blockIdx.y * BB + r] = m;
    ps[blockIdx.y * BB + r] = s;
}

__global__ __launch_bounds__(1024)
void final_k(const float* __restrict__ pm, const float* __restrict__ ps,
             const float* __restrict__ lqz, const float* __restrict__ lpx_part,
             int nt, float* __restrict__ out)
{
    int tid = threadIdx.x;
    float a_ne = 0.f, a_kl = 0.f, a_re = 0.f;
    for (int r = tid; r < BB; r += 1024) {
        float M = -1e30f;
        #pragma unroll
        for (int i = 0; i < NSPLIT; ++i) M = fmaxf(M, pm[i * BB + r]);
        float S = 0.f;
        #pragma unroll
        for (int i = 0; i < NSPLIT; ++i) S += ps[i * BB + r] * expf(pm[i * BB + r] - M);
        float lpz = M + logf(S) - logf((float)KK);
        float lpx = 0.f;
        for (int t = 0; t < nt; ++t) lpx += lpx_part[(size_t)t * BB + r];
        float kl = lqz[r] - lpz;
        a_ne += -lpx + kl;
        a_kl += kl;
        a_re += -lpx;
    }
    __shared__ float red[1024][3];
    red[tid][0] = a_ne; red[tid][1] = a_kl; red[tid][2] = a_re;
    __syncthreads();
    for (int off = 512; off > 0; off >>= 1) {
        if (tid < off) {
            red[tid][0] += red[tid + off][0];
            red[tid][1] += red[tid + off][1];
            red[tid][2] += red[tid + off][2];
        }
        __syncthreads();
    }
    if (tid == 0) {
        out[0] = red[0][0] / (float)BB;
        out[1] = red[0][1] / (float)BB;
        out[2] = red[0][2] / (float)BB;
    }
}

extern "C" void kernel_launch(void* const* d_in, const int* in_sizes, int n_in,
                              void* d_out, int out_size, void* d_ws, size_t ws_size,
                              hipStream_t stream)
{
    const float* x    = (const float*)d_in[0];
    const float* eps  = (const float*)d_in[1];
    const float* zpre = (const float*)d_in[2];
    const float* ew1  = (const float*)d_in[3];
    const float* eb1  = (const float*)d_in[4];
    const float* ew2  = (const float*)d_in[5];
    const float* eb2  = (const float*)d_in[6];
    const float* ew3  = (const float*)d_in[7];
    const float* eb3  = (const float*)d_in[8];
    const float* dw1  = (const float*)d_in[9];
    const float* db1  = (const float*)d_in[10];
    const float* dw2  = (const float*)d_in[11];
    const float* db2  = (const float*)d_in[12];
    const float* dw3  = (const float*)d_in[13];
    const float* db3  = (const float*)d_in[14];
    float* out = (float*)d_out;

    float* ws   = (float*)d_ws;
    float* h1   = ws;                              // B*H
    float* h2   = h1 + (size_t)BB * HH;            // B*H
    float* h3   = h2 + (size_t)BB * HH;            // B*2Z
    float* z    = h3 + (size_t)BB * 2 * ZD;        // B*Z
    float* lqz  = z + (size_t)BB * ZD;             // B
    float* lpx  = lqz + BB;                        // 13*B
    float* coef = lpx + (size_t)13 * BB;           // 21*K
    float* pm   = coef + 21 * KK;                  // NSPLIT*B
    float* ps   = pm + (size_t)NSPLIT * BB;        // NSPLIT*B

    dim3 blk(256);
    const int nt = (XD + 63) / 64;  // 13

    // encoder
    gemm_k<1><<<dim3((HH + 63) / 64, BB / 64), blk, 0, stream>>>(
        x, ew1, eb1, h1, nullptr, nullptr, BB, HH, XD);
    gemm_k<1><<<dim3((HH + 63) / 64, BB / 64), blk, 0, stream>>>(
        h1, ew2, eb2, h2, nullptr, nullptr, BB, HH, HH);
    gemm_k<0><<<dim3(1, BB / 64), blk, 0, stream>>>(
        h2, ew3, eb3, h3, nullptr, nullptr, BB, 2 * ZD, HH);
    reparam_k<<<BB / 256, blk, 0, stream>>>(h3, eps, z, lqz);
    coef_k<<<(KK + 255) / 256, blk, 0, stream>>>(zpre, coef);
    // decoder (reuse h1/h2)
    gemm_k<1><<<dim3((HH + 63) / 64, BB / 64), blk, 0, stream>>>(
        z, dw1, db1, h1, nullptr, nullptr, BB, HH, ZD);
    gemm_k<1><<<dim3((HH + 63) / 64, BB / 64), blk, 0, stream>>>(
        h1, dw2, db2, h2, nullptr, nullptr, BB, HH, HH);
    gemm_k<2><<<dim3((XD + 63) / 64, BB / 64), blk, 0, stream>>>(
        h2, dw3, db3, nullptr, x, lpx, BB, XD, HH);
    // GMM prior logsumexp
    comp_k<<<dim3(BB / 256, NSPLIT), blk, 0, stream>>>(z, coef, pm, ps);
    // finalize
    final_k<<<1, 1024, 0, stream>>>(pm, ps, lqz, lpx, nt, out);
}

// Round 2
// 326.849 us; speedup vs baseline: 1.6438x; 1.6438x over previous
//
#include <hip/hip_runtime.h>
#include <hip/hip_bf16.h>
#include <math.h>

#define BB 8192
#define XD 784
#define ZD 10
#define KK 2000
#define HH 300
#define NSPLIT 8

typedef short short8 __attribute__((ext_vector_type(8)));
typedef float f32x4 __attribute__((ext_vector_type(4)));

__device__ __forceinline__ float sp_(float x) {
    return fmaxf(x, 0.f) + log1pf(expf(-fabsf(x)));
}
__device__ __forceinline__ float elu_(float x) { return x > 0.f ? x : expm1f(x); }
__device__ __forceinline__ unsigned short bf16_(float v) {
    __hip_bfloat16 h = __float2bfloat16(v);
    return __builtin_bit_cast(unsigned short, h);
}

__device__ __forceinline__ void gl16(const unsigned short* g, unsigned short* l) {
    __builtin_amdgcn_global_load_lds(
        (const __attribute__((address_space(1))) unsigned int*)g,
        (__attribute__((address_space(3))) unsigned int*)l, 16, 0, 0);
}

// ---------------------------------------------------------------------------
// bf16 MFMA GEMM: C[M,N] = act(A[M,KP] @ Wt[N,KP]^T + bias)
// A: bf16 [BB][KP] (K zero-padded to KP, mult of 32)
// Wt: bf16 [NP64][KP] (transposed weights, zero-padded)
// Tile: BM=128, BN=64, BK=32; 4 waves, each 64x32 (4x2 frags of 16x16x32).
// LDS fragment-major: chunk c (16B) holds rows m=(c>>6)*16+(c&15),
// k=((c>>4)&3)*8..+7 -> fragment read at Mf*1024 + lane*16 is contiguous.
// MODE 0: store fp32 (stride N, c<N). MODE 1: store bf16 elu (stride NST,
// zero pad cols). MODE 2: fused sum_c(X*logit - softplus(logit)) -> lpx.
// ---------------------------------------------------------------------------
template<int MODE>
__global__ __launch_bounds__(256)
void mgemm(const unsigned short* __restrict__ Ab, const unsigned short* __restrict__ Wt,
           const float* __restrict__ bias, unsigned short* __restrict__ Cb,
           float* __restrict__ Cf, const float* __restrict__ X,
           float* __restrict__ lpx, int KP, int N, int NST)
{
    __shared__ __align__(16) unsigned short lds[128 * 32 + 64 * 32];
    __shared__ float red[128][2];
    const int tid = threadIdx.x;
    const int w = tid >> 6, l = tid & 63;
    const int wr = w >> 1, wc = w & 1;
    const int m0 = blockIdx.y * 128, n0 = blockIdx.x * 64;

    // staging: A chunks 0..511 (8KB), B chunks 0..255 (4KB)
    const int cA0 = (w * 2 + 0) * 64 + l;
    const int cA1 = (w * 2 + 1) * 64 + l;
    const int cB = w * 64 + l;
    const unsigned short* gA0 = Ab + (size_t)(m0 + ((cA0 >> 6) << 4) + (cA0 & 15)) * KP + ((cA0 >> 4) & 3) * 8;
    const unsigned short* gA1 = Ab + (size_t)(m0 + ((cA1 >> 6) << 4) + (cA1 & 15)) * KP + ((cA1 >> 4) & 3) * 8;
    const unsigned short* gB  = Wt + (size_t)(n0 + ((cB >> 6) << 4) + (cB & 15)) * KP + ((cB >> 4) & 3) * 8;
    unsigned short* dA0 = &lds[(w * 2 + 0) * 512];
    unsigned short* dA1 = &lds[(w * 2 + 1) * 512];
    unsigned short* dB  = &lds[4096 + w * 512];

    f32x4 acc[4][2];
    #pragma unroll
    for (int i = 0; i < 4; ++i)
        #pragma unroll
        for (int j = 0; j < 2; ++j)
            acc[i][j] = (f32x4){0.f, 0.f, 0.f, 0.f};

    for (int kb = 0; kb < KP; kb += 32) {
        gl16(gA0 + kb, dA0);
        gl16(gA1 + kb, dA1);
        gl16(gB + kb, dB);
        __syncthreads();   // drains vmcnt -> LDS data visible
        short8 af[4], bfr[2];
        #pragma unroll
        for (int mf = 0; mf < 4; ++mf)
            af[mf] = *reinterpret_cast<const short8*>(&lds[(wr * 4 + mf) * 512 + l * 8]);
        #pragma unroll
        for (int nf = 0; nf < 2; ++nf)
            bfr[nf] = *reinterpret_cast<const short8*>(&lds[4096 + (wc * 2 + nf) * 512 + l * 8]);
        #pragma unroll
        for (int mf = 0; mf < 4; ++mf)
            #pragma unroll
            for (int nf = 0; nf < 2; ++nf)
                acc[mf][nf] = __builtin_amdgcn_mfma_f32_16x16x32_bf16(af[mf], bfr[nf], acc[mf][nf], 0, 0, 0);
        __syncthreads();   // all reads done before next overwrite
    }

    const int cl = l & 15;
    const int g4 = (l >> 4) * 4;
    if (MODE == 2) {
        #pragma unroll
        for (int mf = 0; mf < 4; ++mf) {
            #pragma unroll
            for (int r = 0; r < 4; ++r) {
                const int row = m0 + wr * 64 + mf * 16 + g4 + r;
                float s = 0.f;
                #pragma unroll
                for (int nf = 0; nf < 2; ++nf) {
                    const int c = n0 + wc * 32 + nf * 16 + cl;
                    if (c < N) {
                        float lv = acc[mf][nf][r] + bias[c];
                        s += X[(size_t)row * N + c] * lv - sp_(lv);
                    }
                }
                s += __shfl_xor(s, 1); s += __shfl_xor(s, 2);
                s += __shfl_xor(s, 4); s += __shfl_xor(s, 8);
                if (cl == 0) red[wr * 64 + mf * 16 + g4 + r][wc] = s;
            }
        }
        __syncthreads();
        if (tid < 128)
            lpx[(size_t)blockIdx.x * BB + m0 + tid] = red[tid][0] + red[tid][1];
    } else {
        #pragma unroll
        for (int mf = 0; mf < 4; ++mf) {
            #pragma unroll
            for (int r = 0; r < 4; ++r) {
                const int row = m0 + wr * 64 + mf * 16 + g4 + r;
                #pragma unroll
                for (int nf = 0; nf < 2; ++nf) {
                    const int c = n0 + wc * 32 + nf * 16 + cl;
                    float v = acc[mf][nf][r] + ((c < N) ? bias[c] : 0.f);
                    if (MODE == 0) {
                        if (c < N) Cf[(size_t)row * N + c] = v;
                    } else {
                        float o = (c < N) ? elu_(v) : 0.f;
                        if (c < NST) Cb[(size_t)row * NST + c] = bf16_(o);
                    }
                }
            }
        }
    }
}

// x[8192][784] fp32 -> xb[8192][800] bf16 zero-padded, 4 elems/thread
__global__ __launch_bounds__(256)
void conv_x_k(const float* __restrict__ x, unsigned short* __restrict__ xb)
{
    int idx = blockIdx.x * 256 + threadIdx.x;
    int r = idx / 200, c4 = (idx - r * 200) * 4;
    if (r >= BB) return;
    unsigned int u0 = 0, u1 = 0;
    if (c4 < XD) {
        float4 v = *reinterpret_cast<const float4*>(&x[(size_t)r * XD + c4]);
        u0 = (unsigned)bf16_(v.x) | ((unsigned)bf16_(v.y) << 16);
        u1 = (unsigned)bf16_(v.z) | ((unsigned)bf16_(v.w) << 16);
    }
    uint2 u; u.x = u0; u.y = u1;
    *reinterpret_cast<uint2*>(&xb[(size_t)r * 800 + c4]) = u;
}

// W[K][N] fp32 -> Wt[NP][KP] bf16 transposed, zero-padded
__global__ __launch_bounds__(256)
void conv_w_k(const float* __restrict__ W, unsigned short* __restrict__ Wt,
              int K, int N, int KP, int NP)
{
    int idx = blockIdx.x * 256 + threadIdx.x;
    if (idx >= NP * KP) return;
    int n = idx / KP, k = idx - n * KP;
    float v = (n < N && k < K) ? W[(size_t)k * N + n] : 0.f;
    Wt[idx] = bf16_(v);
}

// h3[B,20] -> z (fp32 + bf16 padded), log_qz
__global__ __launch_bounds__(256)
void reparam_k(const float* __restrict__ h3, const float* __restrict__ eps,
               float* __restrict__ z, unsigned short* __restrict__ zb,
               float* __restrict__ lqz)
{
    int r = blockIdx.x * blockDim.x + threadIdx.x;
    if (r >= BB) return;
    float acc = 0.f;
    #pragma unroll
    for (int j = 0; j < ZD; ++j) {
        float qm = h3[r * 2 * ZD + j];
        float qh = h3[r * 2 * ZD + ZD + j];
        float qv = sp_(qh) + 1e-8f;
        float e = eps[r * ZD + j];
        float zj = qm + sqrtf(qv) * e;
        z[r * ZD + j] = zj;
        zb[r * 32 + j] = bf16_(zj);
        float d = zj - qm;
        acc += logf(6.283185307179586f * qv) + d * d / qv;
    }
    #pragma unroll
    for (int j = ZD; j < 32; ++j) zb[r * 32 + j] = 0;
    lqz[r] = -0.5f * acc;
}

__global__ __launch_bounds__(256)
void coef_k(const float* __restrict__ zpre, float* __restrict__ coef)
{
    int k = blockIdx.x * blockDim.x + threadIdx.x;
    if (k >= KK) return;
    float csum = 0.f;
    #pragma unroll
    for (int j = 0; j < ZD; ++j) {
        float m = zpre[k * ZD + j];
        float h = zpre[(KK + k) * ZD + j];
        float v = sp_(h) + 1e-8f;
        coef[j * KK + k] = -0.5f / v;
        coef[(ZD + j) * KK + k] = m / v;
        csum += logf(6.283185307179586f * v) + m * m / v;
    }
    coef[2 * ZD * KK + k] = -0.5f * csum;
}

__global__ __launch_bounds__(256)
void comp_k(const float* __restrict__ z, const float* __restrict__ coef,
            float* __restrict__ pm, float* __restrict__ ps)
{
    int r = blockIdx.x * 256 + threadIdx.x;
    float zr[ZD], f2[ZD];
    #pragma unroll
    for (int j = 0; j < ZD; ++j) {
        zr[j] = z[r * ZD + j];
        f2[j] = zr[j] * zr[j];
    }
    int kb = blockIdx.y * (KK / NSPLIT);
    int ke = kb + KK / NSPLIT;
    float m = -1e30f, s = 0.f;
    for (int k = kb; k < ke; ++k) {
        float c = coef[2 * ZD * KK + k];
        #pragma unroll
        for (int j = 0; j < ZD; ++j) c = fmaf(f2[j], coef[j * KK + k], c);
        #pragma unroll
        for (int j = 0; j < ZD; ++j) c = fmaf(zr[j], coef[(ZD + j) * KK + k], c);
        if (c > m) { s = s * expf(m - c) + 1.f; m = c; }
        else       { s += expf(c - m); }
    }
    pm[blockIdx.y * BB + r] = m;
    ps[blockIdx.y * BB + r] = s;
}

__global__ __launch_bounds__(1024)
void final_k(const float* __restrict__ pm, const float* __restrict__ ps,
             const float* __restrict__ lqz, const float* __restrict__ lpx_part,
             int nt, float* __restrict__ out)
{
    int tid = threadIdx.x;
    float a_ne = 0.f, a_kl = 0.f, a_re = 0.f;
    for (int r = tid; r < BB; r += 1024) {
        float M = -1e30f;
        #pragma unroll
        for (int i = 0; i < NSPLIT; ++i) M = fmaxf(M, pm[i * BB + r]);
        float S = 0.f;
        #pragma unroll
        for (int i = 0; i < NSPLIT; ++i) S += ps[i * BB + r] * expf(pm[i * BB + r] - M);
        float lpz = M + logf(S) - logf((float)KK);
        float lpx = 0.f;
        for (int t = 0; t < nt; ++t) lpx += lpx_part[(size_t)t * BB + r];
        float kl = lqz[r] - lpz;
        a_ne += -lpx + kl;
        a_kl += kl;
        a_re += -lpx;
    }
    __shared__ float red[1024][3];
    red[tid][0] = a_ne; red[tid][1] = a_kl; red[tid][2] = a_re;
    __syncthreads();
    for (int off = 512; off > 0; off >>= 1) {
        if (tid < off) {
            red[tid][0] += red[tid + off][0];
            red[tid][1] += red[tid + off][1];
            red[tid][2] += red[tid + off][2];
        }
        __syncthreads();
    }
    if (tid == 0) {
        out[0] = red[0][0] / (float)BB;
        out[1] = red[0][1] / (float)BB;
        out[2] = red[0][2] / (float)BB;
    }
}

extern "C" void kernel_launch(void* const* d_in, const int* in_sizes, int n_in,
                              void* d_out, int out_size, void* d_ws, size_t ws_size,
                              hipStream_t stream)
{
    const float* x    = (const float*)d_in[0];
    const float* eps  = (const float*)d_in[1];
    const float* zpre = (const float*)d_in[2];
    const float* ew1  = (const float*)d_in[3];
    const float* eb1  = (const float*)d_in[4];
    const float* ew2  = (const float*)d_in[5];
    const float* eb2  = (const float*)d_in[6];
    const float* ew3  = (const float*)d_in[7];
    const float* eb3  = (const float*)d_in[8];
    const float* dw1  = (const float*)d_in[9];
    const float* db1  = (const float*)d_in[10];
    const float* dw2  = (const float*)d_in[11];
    const float* db2  = (const float*)d_in[12];
    const float* dw3  = (const float*)d_in[13];
    const float* db3  = (const float*)d_in[14];
    float* out = (float*)d_out;

    float* ws   = (float*)d_ws;
    float* h3   = ws;                            // BB*20
    float* z    = h3 + (size_t)BB * 2 * ZD;      // BB*10
    float* lqz  = z + (size_t)BB * ZD;           // BB
    float* lpx  = lqz + BB;                      // 13*BB
    float* coef = lpx + (size_t)13 * BB;         // 21*KK
    float* pm   = coef + 21 * KK;                // 8*BB
    float* ps   = pm + (size_t)NSPLIT * BB;      // 8*BB

    unsigned short* ub = (unsigned short*)(ps + (size_t)NSPLIT * BB);
    unsigned short* xb  = ub; ub += (size_t)BB * 800;
    unsigned short* h1b = ub; ub += (size_t)BB * 320;
    unsigned short* h2b = ub; ub += (size_t)BB * 320;
    unsigned short* zb  = ub; ub += (size_t)BB * 32;
    unsigned short* w1t = ub; ub += 320 * 800;
    unsigned short* w2t = ub; ub += 320 * 320;
    unsigned short* w3t = ub; ub += 64 * 320;
    unsigned short* d1t = ub; ub += 320 * 32;
    unsigned short* d2t = ub; ub += 320 * 320;
    unsigned short* d3t = ub; ub += 832 * 320;

    dim3 blk(256);

    conv_x_k<<<(BB * 200) / 256, blk, 0, stream>>>(x, xb);
    conv_w_k<<<(320 * 800 + 255) / 256, blk, 0, stream>>>(ew1, w1t, XD, HH, 800, 320);
    conv_w_k<<<(320 * 320 + 255) / 256, blk, 0, stream>>>(ew2, w2t, HH, HH, 320, 320);
    conv_w_k<<<(64 * 320 + 255) / 256, blk, 0, stream>>>(ew3, w3t, HH, 2 * ZD, 320, 64);
    conv_w_k<<<(320 * 32 + 255) / 256, blk, 0, stream>>>(dw1, d1t, ZD, HH, 32, 320);
    conv_w_k<<<(320 * 320 + 255) / 256, blk, 0, stream>>>(dw2, d2t, HH, HH, 320, 320);
    conv_w_k<<<(832 * 320 + 255) / 256, blk, 0, stream>>>(dw3, d3t, HH, XD, 320, 832);
    coef_k<<<(KK + 255) / 256, blk, 0, stream>>>(zpre, coef);

    // encoder
    mgemm<1><<<dim3(5, 64), blk, 0, stream>>>(xb, w1t, eb1, h1b, nullptr, nullptr, nullptr, 800, HH, 320);
    mgemm<1><<<dim3(5, 64), blk, 0, stream>>>(h1b, w2t, eb2, h2b, nullptr, nullptr, nullptr, 320, HH, 320);
    mgemm<0><<<dim3(1, 64), blk, 0, stream>>>(h2b, w3t, eb3, nullptr, h3, nullptr, nullptr, 320, 2 * ZD, 0);
    reparam_k<<<BB / 256, blk, 0, stream>>>(h3, eps, z, zb, lqz);
    // decoder
    mgemm<1><<<dim3(5, 64), blk, 0, stream>>>(zb, d1t, db1, h1b, nullptr, nullptr, nullptr, 32, HH, 320);
    mgemm<1><<<dim3(5, 64), blk, 0, stream>>>(h1b, d2t, db2, h2b, nullptr, nullptr, nullptr, 320, HH, 320);
    mgemm<2><<<dim3(13, 64), blk, 0, stream>>>(h2b, d3t, db3, nullptr, nullptr, x, lpx, 320, XD, 0);
    // GMM prior
    comp_k<<<dim3(BB / 256, NSPLIT), blk, 0, stream>>>(z, coef, pm, ps);
    final_k<<<1, 1024, 0, stream>>>(pm, ps, lqz, lpx, 13, out);
}

// Round 3
// 202.632 us; speedup vs baseline: 2.6515x; 1.6130x over previous
//
#include <hip/hip_runtime.h>
#include <hip/hip_bf16.h>
#include <math.h>

#define BB 8192
#define XD 784
#define ZD 10
#define KK 2000
#define HH 300
#define NSP 32          // column tiles of the comp GEMM (2048/64)

typedef short short8 __attribute__((ext_vector_type(8)));
typedef float f32x4 __attribute__((ext_vector_type(4)));

__device__ __forceinline__ float sp_(float x) {
    return fmaxf(x, 0.f) + log1pf(expf(-fabsf(x)));
}
__device__ __forceinline__ float elu_(float x) { return x > 0.f ? x : expm1f(x); }
__device__ __forceinline__ unsigned short bf16_(float v) {
    __hip_bfloat16 h = __float2bfloat16(v);
    return __builtin_bit_cast(unsigned short, h);
}

__device__ __forceinline__ void gl16(const unsigned short* g, unsigned short* l) {
    __builtin_amdgcn_global_load_lds(
        (const __attribute__((address_space(1))) unsigned int*)g,
        (__attribute__((address_space(3))) unsigned int*)l, 16, 0, 0);
}

// ---------------------------------------------------------------------------
// bf16 MFMA GEMM: C[M,N] = act(A[M,KP] @ Wt[N,KP]^T + bias)
// Tile: BM=128, BN=64, BK=32; 4 waves, each 64x32 (4x2 frags of 16x16x32).
// LDS fragment-major (see r1): staging is linear, ds_read_b128 contiguous.
// MODE 0: store fp32. MODE 1: store bf16 elu (stride NST, zero-pad cols).
// MODE 2: fused sum_c(X*logit - softplus(logit)) -> lpx (per n-tile partial).
// MODE 3: per-row online logsumexp over the 64-col tile -> pm (via Cf),
//         ps (via lpx). bias = c_k (fp32), padded cols have bias=-1e30.
// ---------------------------------------------------------------------------
template<int MODE>
__global__ __launch_bounds__(256)
void mgemm(const unsigned short* __restrict__ Ab, const unsigned short* __restrict__ Wt,
           const float* __restrict__ bias, unsigned short* __restrict__ Cb,
           float* __restrict__ Cf, const float* __restrict__ X,
           float* __restrict__ lpx, int KP, int N, int NST)
{
    __shared__ __align__(16) unsigned short lds[128 * 32 + 64 * 32];
    __shared__ float redm[128][2];
    __shared__ float reds[128][2];
    const int tid = threadIdx.x;
    const int w = tid >> 6, l = tid & 63;
    const int wr = w >> 1, wc = w & 1;
    const int mb0 = blockIdx.y * 128, n0 = blockIdx.x * 64;

    const int cA0 = (w * 2 + 0) * 64 + l;
    const int cA1 = (w * 2 + 1) * 64 + l;
    const int cB = w * 64 + l;
    const unsigned short* gA0 = Ab + (size_t)(mb0 + ((cA0 >> 6) << 4) + (cA0 & 15)) * KP + ((cA0 >> 4) & 3) * 8;
    const unsigned short* gA1 = Ab + (size_t)(mb0 + ((cA1 >> 6) << 4) + (cA1 & 15)) * KP + ((cA1 >> 4) & 3) * 8;
    const unsigned short* gB  = Wt + (size_t)(n0 + ((cB >> 6) << 4) + (cB & 15)) * KP + ((cB >> 4) & 3) * 8;
    unsigned short* dA0 = &lds[(w * 2 + 0) * 512];
    unsigned short* dA1 = &lds[(w * 2 + 1) * 512];
    unsigned short* dB  = &lds[4096 + w * 512];

    f32x4 acc[4][2];
    #pragma unroll
    for (int i = 0; i < 4; ++i)
        #pragma unroll
        for (int j = 0; j < 2; ++j)
            acc[i][j] = (f32x4){0.f, 0.f, 0.f, 0.f};

    for (int kb = 0; kb < KP; kb += 32) {
        gl16(gA0 + kb, dA0);
        gl16(gA1 + kb, dA1);
        gl16(gB + kb, dB);
        __syncthreads();
        short8 af[4], bfr[2];
        #pragma unroll
        for (int mf = 0; mf < 4; ++mf)
            af[mf] = *reinterpret_cast<const short8*>(&lds[(wr * 4 + mf) * 512 + l * 8]);
        #pragma unroll
        for (int nf = 0; nf < 2; ++nf)
            bfr[nf] = *reinterpret_cast<const short8*>(&lds[4096 + (wc * 2 + nf) * 512 + l * 8]);
        #pragma unroll
        for (int mf = 0; mf < 4; ++mf)
            #pragma unroll
            for (int nf = 0; nf < 2; ++nf)
                acc[mf][nf] = __builtin_amdgcn_mfma_f32_16x16x32_bf16(af[mf], bfr[nf], acc[mf][nf], 0, 0, 0);
        __syncthreads();
    }

    const int cl = l & 15;
    const int g4 = (l >> 4) * 4;
    if (MODE == 3) {
        const float b0 = bias[n0 + wc * 32 + cl];
        const float b1 = bias[n0 + wc * 32 + 16 + cl];
        #pragma unroll
        for (int mf = 0; mf < 4; ++mf) {
            #pragma unroll
            for (int r = 0; r < 4; ++r) {
                float v0 = acc[mf][0][r] + b0;
                float v1 = acc[mf][1][r] + b1;
                float mx = fmaxf(v0, v1);
                mx = fmaxf(mx, __shfl_xor(mx, 1));
                mx = fmaxf(mx, __shfl_xor(mx, 2));
                mx = fmaxf(mx, __shfl_xor(mx, 4));
                mx = fmaxf(mx, __shfl_xor(mx, 8));
                float s = expf(v0 - mx) + expf(v1 - mx);
                s += __shfl_xor(s, 1); s += __shfl_xor(s, 2);
                s += __shfl_xor(s, 4); s += __shfl_xor(s, 8);
                if (cl == 0) {
                    int rl = wr * 64 + mf * 16 + g4 + r;
                    redm[rl][wc] = mx;
                    reds[rl][wc] = s;
                }
            }
        }
        __syncthreads();
        if (tid < 128) {
            float m0 = redm[tid][0], m1 = redm[tid][1];
            float M = fmaxf(m0, m1);
            float S = reds[tid][0] * expf(m0 - M) + reds[tid][1] * expf(m1 - M);
            Cf[(size_t)blockIdx.x * BB + mb0 + tid] = M;    // pm
            lpx[(size_t)blockIdx.x * BB + mb0 + tid] = S;   // ps
        }
    } else if (MODE == 2) {
        #pragma unroll
        for (int mf = 0; mf < 4; ++mf) {
            #pragma unroll
            for (int r = 0; r < 4; ++r) {
                const int row = mb0 + wr * 64 + mf * 16 + g4 + r;
                float s = 0.f;
                #pragma unroll
                for (int nf = 0; nf < 2; ++nf) {
                    const int c = n0 + wc * 32 + nf * 16 + cl;
                    if (c < N) {
                        float lv = acc[mf][nf][r] + bias[c];
                        s += X[(size_t)row * N + c] * lv - sp_(lv);
                    }
                }
                s += __shfl_xor(s, 1); s += __shfl_xor(s, 2);
                s += __shfl_xor(s, 4); s += __shfl_xor(s, 8);
                if (cl == 0) redm[wr * 64 + mf * 16 + g4 + r][wc] = s;
            }
        }
        __syncthreads();
        if (tid < 128)
            lpx[(size_t)blockIdx.x * BB + mb0 + tid] = redm[tid][0] + redm[tid][1];
    } else {
        #pragma unroll
        for (int mf = 0; mf < 4; ++mf) {
            #pragma unroll
            for (int r = 0; r < 4; ++r) {
                const int row = mb0 + wr * 64 + mf * 16 + g4 + r;
                #pragma unroll
                for (int nf = 0; nf < 2; ++nf) {
                    const int c = n0 + wc * 32 + nf * 16 + cl;
                    float v = acc[mf][nf][r] + ((c < N) ? bias[c] : 0.f);
                    if (MODE == 0) {
                        if (c < N) Cf[(size_t)row * N + c] = v;
                    } else {
                        float o = (c < N) ? elu_(v) : 0.f;
                        if (c < NST) Cb[(size_t)row * NST + c] = bf16_(o);
                    }
                }
            }
        }
    }
}

// x[8192][784] fp32 -> xb[8192][800] bf16 zero-padded
__global__ __launch_bounds__(256)
void conv_x_k(const float* __restrict__ x, unsigned short* __restrict__ xb)
{
    int idx = blockIdx.x * 256 + threadIdx.x;
    int r = idx / 200, c4 = (idx - r * 200) * 4;
    if (r >= BB) return;
    unsigned int u0 = 0, u1 = 0;
    if (c4 < XD) {
        float4 v = *reinterpret_cast<const float4*>(&x[(size_t)r * XD + c4]);
        u0 = (unsigned)bf16_(v.x) | ((unsigned)bf16_(v.y) << 16);
        u1 = (unsigned)bf16_(v.z) | ((unsigned)bf16_(v.w) << 16);
    }
    uint2 u; u.x = u0; u.y = u1;
    *reinterpret_cast<uint2*>(&xb[(size_t)r * 800 + c4]) = u;
}

// W[K][N] fp32 -> Wt[NP][KP] bf16 transposed, zero-padded
__global__ __launch_bounds__(256)
void conv_w_k(const float* __restrict__ W, unsigned short* __restrict__ Wt,
              int K, int N, int KP, int NP)
{
    int idx = blockIdx.x * 256 + threadIdx.x;
    if (idx >= NP * KP) return;
    int n = idx / KP, k = idx - n * KP;
    float v = (n < N && k < K) ? W[(size_t)k * N + n] : 0.f;
    Wt[idx] = bf16_(v);
}

// h3[B,20] -> zb (decoder input, padded 32), fb ([z^2, z] padded 32), log_qz
__global__ __launch_bounds__(256)
void reparam_k(const float* __restrict__ h3, const float* __restrict__ eps,
               unsigned short* __restrict__ zb, unsigned short* __restrict__ fb,
               float* __restrict__ lqz)
{
    int r = blockIdx.x * blockDim.x + threadIdx.x;
    if (r >= BB) return;
    float acc = 0.f;
    #pragma unroll
    for (int j = 0; j < ZD; ++j) {
        float qm = h3[r * 2 * ZD + j];
        float qh = h3[r * 2 * ZD + ZD + j];
        float qv = sp_(qh) + 1e-8f;
        float e = eps[r * ZD + j];
        float zj = qm + sqrtf(qv) * e;
        zb[r * 32 + j] = bf16_(zj);
        fb[r * 32 + j] = bf16_(zj * zj);
        fb[r * 32 + ZD + j] = bf16_(zj);
        float d = zj - qm;
        acc += logf(6.283185307179586f * qv) + d * d / qv;
    }
    #pragma unroll
    for (int j = ZD; j < 32; ++j) zb[r * 32 + j] = 0;
    #pragma unroll
    for (int j = 2 * ZD; j < 32; ++j) fb[r * 32 + j] = 0;
    lqz[r] = -0.5f * acc;
}

// GMM prior -> G bf16 [2048][32] = [-0.5/v, m/v, pad]; cbias fp32 [2048] = c_k
__global__ __launch_bounds__(256)
void coef_k(const float* __restrict__ zpre, unsigned short* __restrict__ G,
            float* __restrict__ cbias)
{
    int k = blockIdx.x * blockDim.x + threadIdx.x;
    if (k >= 2048) return;
    if (k < KK) {
        float csum = 0.f;
        #pragma unroll
        for (int j = 0; j < ZD; ++j) {
            float m = zpre[k * ZD + j];
            float h = zpre[(KK + k) * ZD + j];
            float v = sp_(h) + 1e-8f;
            G[k * 32 + j] = bf16_(-0.5f / v);
            G[k * 32 + ZD + j] = bf16_(m / v);
            csum += logf(6.283185307179586f * v) + m * m / v;
        }
        #pragma unroll
        for (int j = 2 * ZD; j < 32; ++j) G[k * 32 + j] = 0;
        cbias[k] = -0.5f * csum;
    } else {
        #pragma unroll
        for (int j = 0; j < 32; ++j) G[k * 32 + j] = 0;
        cbias[k] = -1e30f;
    }
}

// stage-1 reduce: per-row lpz/kl/lpx, then block partial sums -> part[32][3]
__global__ __launch_bounds__(256)
void row_k(const float* __restrict__ pm, const float* __restrict__ ps,
           const float* __restrict__ lqz, const float* __restrict__ lpx_part,
           float* __restrict__ part)
{
    int r = blockIdx.x * 256 + threadIdx.x;
    float M = -1e30f;
    #pragma unroll
    for (int i = 0; i < NSP; ++i) M = fmaxf(M, pm[(size_t)i * BB + r]);
    float S = 0.f;
    #pragma unroll
    for (int i = 0; i < NSP; ++i) S += ps[(size_t)i * BB + r] * expf(pm[(size_t)i * BB + r] - M);
    float lpz = M + logf(S) - 7.6009024595420824f;  // log(2000)
    float lp = 0.f;
    #pragma unroll
    for (int t = 0; t < 13; ++t) lp += lpx_part[(size_t)t * BB + r];
    float kl = lqz[r] - lpz;
    float ne = kl - lp, re = -lp;
    #pragma unroll
    for (int d = 1; d < 64; d <<= 1) {
        ne += __shfl_xor(ne, d);
        kl += __shfl_xor(kl, d);
        re += __shfl_xor(re, d);
    }
    __shared__ float sm[4][3];
    int l = threadIdx.x & 63, w = threadIdx.x >> 6;
    if (l == 0) { sm[w][0] = ne; sm[w][1] = kl; sm[w][2] = re; }
    __syncthreads();
    if (threadIdx.x == 0) {
        part[blockIdx.x * 3 + 0] = sm[0][0] + sm[1][0] + sm[2][0] + sm[3][0];
        part[blockIdx.x * 3 + 1] = sm[0][1] + sm[1][1] + sm[2][1] + sm[3][1];
        part[blockIdx.x * 3 + 2] = sm[0][2] + sm[1][2] + sm[2][2] + sm[3][2];
    }
}

__global__ void fin_k(const float* __restrict__ part, float* __restrict__ out)
{
    int t = threadIdx.x;   // 0..2
    if (t < 3) {
        float s = 0.f;
        for (int b = 0; b < 32; ++b) s += part[b * 3 + t];
        out[t] = s / (float)BB;
    }
}

extern "C" void kernel_launch(void* const* d_in, const int* in_sizes, int n_in,
                              void* d_out, int out_size, void* d_ws, size_t ws_size,
                              hipStream_t stream)
{
    const float* x    = (const float*)d_in[0];
    const float* eps  = (const float*)d_in[1];
    const float* zpre = (const float*)d_in[2];
    const float* ew1  = (const float*)d_in[3];
    const float* eb1  = (const float*)d_in[4];
    const float* ew2  = (const float*)d_in[5];
    const float* eb2  = (const float*)d_in[6];
    const float* ew3  = (const float*)d_in[7];
    const float* eb3  = (const float*)d_in[8];
    const float* dw1  = (const float*)d_in[9];
    const float* db1  = (const float*)d_in[10];
    const float* dw2  = (const float*)d_in[11];
    const float* db2  = (const float*)d_in[12];
    const float* dw3  = (const float*)d_in[13];
    const float* db3  = (const float*)d_in[14];
    float* out = (float*)d_out;

    float* ws    = (float*)d_ws;
    float* h3    = ws;                            // BB*20
    float* lqz   = h3 + (size_t)BB * 2 * ZD;      // BB
    float* lpx   = lqz + BB;                      // 13*BB
    float* cbias = lpx + (size_t)13 * BB;         // 2048
    float* pm    = cbias + 2048;                  // 32*BB
    float* ps    = pm + (size_t)NSP * BB;         // 32*BB
    float* part  = ps + (size_t)NSP * BB;         // 96

    unsigned short* ub = (unsigned short*)(part + 96);
    unsigned short* xb  = ub; ub += (size_t)BB * 800;
    unsigned short* h1b = ub; ub += (size_t)BB * 320;
    unsigned short* h2b = ub; ub += (size_t)BB * 320;
    unsigned short* zb  = ub; ub += (size_t)BB * 32;
    unsigned short* fb  = ub; ub += (size_t)BB * 32;
    unsigned short* w1t = ub; ub += 320 * 800;
    unsigned short* w2t = ub; ub += 320 * 320;
    unsigned short* w3t = ub; ub += 64 * 320;
    unsigned short* d1t = ub; ub += 320 * 32;
    unsigned short* d2t = ub; ub += 320 * 320;
    unsigned short* d3t = ub; ub += 832 * 320;
    unsigned short* G   = ub; ub += 2048 * 32;

    dim3 blk(256);

    conv_x_k<<<(BB * 200) / 256, blk, 0, stream>>>(x, xb);
    conv_w_k<<<(320 * 800 + 255) / 256, blk, 0, stream>>>(ew1, w1t, XD, HH, 800, 320);
    conv_w_k<<<(320 * 320 + 255) / 256, blk, 0, stream>>>(ew2, w2t, HH, HH, 320, 320);
    conv_w_k<<<(64 * 320 + 255) / 256, blk, 0, stream>>>(ew3, w3t, HH, 2 * ZD, 320, 64);
    conv_w_k<<<(320 * 32 + 255) / 256, blk, 0, stream>>>(dw1, d1t, ZD, HH, 32, 320);
    conv_w_k<<<(320 * 320 + 255) / 256, blk, 0, stream>>>(dw2, d2t, HH, HH, 320, 320);
    conv_w_k<<<(832 * 320 + 255) / 256, blk, 0, stream>>>(dw3, d3t, HH, XD, 320, 832);
    coef_k<<<2048 / 256, blk, 0, stream>>>(zpre, G, cbias);

    // encoder
    mgemm<1><<<dim3(5, 64), blk, 0, stream>>>(xb, w1t, eb1, h1b, nullptr, nullptr, nullptr, 800, HH, 320);
    mgemm<1><<<dim3(5, 64), blk, 0, stream>>>(h1b, w2t, eb2, h2b, nullptr, nullptr, nullptr, 320, HH, 320);
    mgemm<0><<<dim3(1, 64), blk, 0, stream>>>(h2b, w3t, eb3, nullptr, h3, nullptr, nullptr, 320, 2 * ZD, 0);
    reparam_k<<<BB / 256, blk, 0, stream>>>(h3, eps, zb, fb, lqz);
    // decoder
    mgemm<1><<<dim3(5, 64), blk, 0, stream>>>(zb, d1t, db1, h1b, nullptr, nullptr, nullptr, 32, HH, 320);
    mgemm<1><<<dim3(5, 64), blk, 0, stream>>>(h1b, d2t, db2, h2b, nullptr, nullptr, nullptr, 320, HH, 320);
    mgemm<2><<<dim3(13, 64), blk, 0, stream>>>(h2b, d3t, db3, nullptr, nullptr, x, lpx, 320, XD, 0);
    // GMM prior: comp = F @ G^T + c_k, fused logsumexp per 64-col tile
    mgemm<3><<<dim3(NSP, 64), blk, 0, stream>>>(fb, G, cbias, nullptr, pm, nullptr, ps, 32, 2048, 0);
    // finalize
    row_k<<<32, blk, 0, stream>>>(pm, ps, lqz, lpx, part);
    fin_k<<<1, 64, 0, stream>>>(part, out);
}

// Round 4
// 181.358 us; speedup vs baseline: 2.9625x; 1.1173x over previous
//
#include <hip/hip_runtime.h>
#include <hip/hip_bf16.h>
#include <math.h>

#define BB 8192
#define XD 784
#define ZD 10
#define KK 2000
#define HH 300
#define NSP 32          // column tiles of the comp GEMM (2048/64)

typedef short short8 __attribute__((ext_vector_type(8)));
typedef float f32x4 __attribute__((ext_vector_type(4)));

__device__ __forceinline__ float sp_(float x) {
    return fmaxf(x, 0.f) + log1pf(expf(-fabsf(x)));
}
__device__ __forceinline__ float elu_(float x) { return x > 0.f ? x : expm1f(x); }
__device__ __forceinline__ unsigned short bf16_(float v) {
    __hip_bfloat16 h = __float2bfloat16(v);
    return __builtin_bit_cast(unsigned short, h);
}

__device__ __forceinline__ void gl16(const unsigned short* g, unsigned short* l) {
    __builtin_amdgcn_global_load_lds(
        (const __attribute__((address_space(1))) unsigned int*)g,
        (__attribute__((address_space(3))) unsigned int*)l, 16, 0, 0);
}

// ---------------------------------------------------------------------------
// bf16 MFMA GEMM: C[M,N] = act(A[M,KP] @ Wt[N,KP]^T + bias)
// Tile: BM=64, BN=64, BK=64; 4 waves (2x2), each 32x32 = 2x2 frags 16x16x32.
// Double-buffered LDS, 2-phase prefetch, counted vmcnt(4) (never drain
// in-loop), raw s_barrier. LDS fragment-major: chunk-group f (1024B) holds
// 16 rows x 32 k, lane l = row (l&15), k (l>>4)*8; staging is linear so
// global_load_lds(16B) works; ds_read_b128 contiguous (0 conflicts).
// MODE 0: store fp32. MODE 1: store bf16 elu (stride NST, zero-pad cols).
// MODE 2: fused sum_c(X*logit - softplus(logit)) -> lpx (per n-tile partial).
// MODE 3: per-row online logsumexp over 64-col tile -> pm (Cf), ps (lpx),
//         bias = c_k fp32; padded cols have bias=-1e30.
// KP must be a multiple of 64.
// ---------------------------------------------------------------------------
template<int MODE>
__global__ __launch_bounds__(256)
void mgemm(const unsigned short* __restrict__ Ab, const unsigned short* __restrict__ Wt,
           const float* __restrict__ bias, unsigned short* __restrict__ Cb,
           float* __restrict__ Cf, const float* __restrict__ X,
           float* __restrict__ lpx, int KP, int N, int NST)
{
    __shared__ __align__(16) unsigned short lds[2][8192];
    __shared__ float redm[64][2];
    __shared__ float reds[64][2];
    const int tid = threadIdx.x;
    const int w = tid >> 6, l = tid & 63;
    const int wr = w >> 1, wc = w & 1;
    const int m0 = blockIdx.y * 64, n0 = blockIdx.x * 64;
    const int rg = l & 15;          // row within 16-row group
    const int kg = (l >> 4) * 8;    // k-offset within 32-k half

    // staging: wave w owns chunk-groups {2w, 2w+1} of A and of B
    const unsigned short* gA0 = Ab + (size_t)(m0 + w * 16 + rg) * KP + kg;
    const unsigned short* gA1 = gA0 + 32;
    const unsigned short* gB0 = Wt + (size_t)(n0 + w * 16 + rg) * KP + kg;
    const unsigned short* gB1 = gB0 + 32;
    unsigned short* sA0 = &lds[0][(2 * w + 0) * 512];
    unsigned short* sA1 = &lds[0][(2 * w + 1) * 512];
    unsigned short* sB0 = &lds[0][4096 + (2 * w + 0) * 512];
    unsigned short* sB1 = &lds[0][4096 + (2 * w + 1) * 512];

    f32x4 acc[2][2];
    #pragma unroll
    for (int i = 0; i < 2; ++i)
        #pragma unroll
        for (int j = 0; j < 2; ++j)
            acc[i][j] = (f32x4){0.f, 0.f, 0.f, 0.f};

    const int nt = KP >> 6;
    // prologue: stage tile 0 into buf 0
    gl16(gA0, sA0); gl16(gA1, sA1); gl16(gB0, sB0); gl16(gB1, sB1);
    int cur = 0;
    for (int t = 0; t < nt; ++t) {
        if (t + 1 < nt) {
            const int kb = (t + 1) << 6;
            const int bo = (cur ^ 1) * 8192;
            gl16(gA0 + kb, sA0 + bo); gl16(gA1 + kb, sA1 + bo);
            gl16(gB0 + kb, sB0 + bo); gl16(gB1 + kb, sB1 + bo);
            asm volatile("s_waitcnt vmcnt(4)" ::: "memory");  // tile t landed
        } else {
            asm volatile("s_waitcnt vmcnt(0)" ::: "memory");
        }
        __builtin_amdgcn_s_barrier();            // all waves' tile-t in LDS
        __builtin_amdgcn_sched_barrier(0);
        const unsigned short* L = &lds[cur][0];
        short8 af[2][2], bv[2][2];
        #pragma unroll
        for (int mf = 0; mf < 2; ++mf)
            #pragma unroll
            for (int s = 0; s < 2; ++s)
                af[mf][s] = *reinterpret_cast<const short8*>(
                    &L[((wr * 2 + mf) * 2 + s) * 512 + l * 8]);
        #pragma unroll
        for (int nf = 0; nf < 2; ++nf)
            #pragma unroll
            for (int s = 0; s < 2; ++s)
                bv[nf][s] = *reinterpret_cast<const short8*>(
                    &L[4096 + ((wc * 2 + nf) * 2 + s) * 512 + l * 8]);
        #pragma unroll
        for (int mf = 0; mf < 2; ++mf)
            #pragma unroll
            for (int nf = 0; nf < 2; ++nf) {
                acc[mf][nf] = __builtin_amdgcn_mfma_f32_16x16x32_bf16(af[mf][0], bv[nf][0], acc[mf][nf], 0, 0, 0);
                acc[mf][nf] = __builtin_amdgcn_mfma_f32_16x16x32_bf16(af[mf][1], bv[nf][1], acc[mf][nf], 0, 0, 0);
            }
        asm volatile("s_waitcnt lgkmcnt(0)" ::: "memory");  // reads drained
        __builtin_amdgcn_sched_barrier(0);
        __builtin_amdgcn_s_barrier();            // buf[cur] free to overwrite
        __builtin_amdgcn_sched_barrier(0);
        cur ^= 1;
    }

    const int cl = l & 15;
    const int g4 = (l >> 4) * 4;
    if (MODE == 3) {
        const float b0 = bias[n0 + wc * 32 + cl];
        const float b1 = bias[n0 + wc * 32 + 16 + cl];
        #pragma unroll
        for (int mf = 0; mf < 2; ++mf) {
            #pragma unroll
            for (int r = 0; r < 4; ++r) {
                float v0 = acc[mf][0][r] + b0;
                float v1 = acc[mf][1][r] + b1;
                float mx = fmaxf(v0, v1);
                mx = fmaxf(mx, __shfl_xor(mx, 1));
                mx = fmaxf(mx, __shfl_xor(mx, 2));
                mx = fmaxf(mx, __shfl_xor(mx, 4));
                mx = fmaxf(mx, __shfl_xor(mx, 8));
                float s = expf(v0 - mx) + expf(v1 - mx);
                s += __shfl_xor(s, 1); s += __shfl_xor(s, 2);
                s += __shfl_xor(s, 4); s += __shfl_xor(s, 8);
                if (cl == 0) {
                    int rl = wr * 32 + mf * 16 + g4 + r;
                    redm[rl][wc] = mx;
                    reds[rl][wc] = s;
                }
            }
        }
        __syncthreads();
        if (tid < 64) {
            float mA = redm[tid][0], mB = redm[tid][1];
            float M = fmaxf(mA, mB);
            float S = reds[tid][0] * expf(mA - M) + reds[tid][1] * expf(mB - M);
            Cf[(size_t)blockIdx.x * BB + m0 + tid] = M;    // pm
            lpx[(size_t)blockIdx.x * BB + m0 + tid] = S;   // ps
        }
    } else if (MODE == 2) {
        #pragma unroll
        for (int mf = 0; mf < 2; ++mf) {
            #pragma unroll
            for (int r = 0; r < 4; ++r) {
                const int row = m0 + wr * 32 + mf * 16 + g4 + r;
                float s = 0.f;
                #pragma unroll
                for (int nf = 0; nf < 2; ++nf) {
                    const int c = n0 + wc * 32 + nf * 16 + cl;
                    if (c < N) {
                        float lv = acc[mf][nf][r] + bias[c];
                        s += X[(size_t)row * N + c] * lv - sp_(lv);
                    }
                }
                s += __shfl_xor(s, 1); s += __shfl_xor(s, 2);
                s += __shfl_xor(s, 4); s += __shfl_xor(s, 8);
                if (cl == 0) redm[wr * 32 + mf * 16 + g4 + r][wc] = s;
            }
        }
        __syncthreads();
        if (tid < 64)
            lpx[(size_t)blockIdx.x * BB + m0 + tid] = redm[tid][0] + redm[tid][1];
    } else {
        #pragma unroll
        for (int mf = 0; mf < 2; ++mf) {
            #pragma unroll
            for (int r = 0; r < 4; ++r) {
                const int row = m0 + wr * 32 + mf * 16 + g4 + r;
                #pragma unroll
                for (int nf = 0; nf < 2; ++nf) {
                    const int c = n0 + wc * 32 + nf * 16 + cl;
                    float bvl = (c < N) ? bias[c] : 0.f;
                    float v = acc[mf][nf][r] + bvl;
                    if (MODE == 0) {
                        if (c < N) Cf[(size_t)row * N + c] = v;
                    } else {
                        float o = (c < N) ? elu_(v) : 0.f;
                        if (c < NST) Cb[(size_t)row * NST + c] = bf16_(o);
                    }
                }
            }
        }
    }
}

// x[8192][784] fp32 -> xb[8192][832] bf16 zero-padded
__global__ __launch_bounds__(256)
void conv_x_k(const float* __restrict__ x, unsigned short* __restrict__ xb)
{
    int idx = blockIdx.x * 256 + threadIdx.x;
    int r = idx / 208, c4 = (idx - r * 208) * 4;
    if (r >= BB) return;
    unsigned int u0 = 0, u1 = 0;
    if (c4 < XD) {
        float4 v = *reinterpret_cast<const float4*>(&x[(size_t)r * XD + c4]);
        u0 = (unsigned)bf16_(v.x) | ((unsigned)bf16_(v.y) << 16);
        u1 = (unsigned)bf16_(v.z) | ((unsigned)bf16_(v.w) << 16);
    }
    uint2 u; u.x = u0; u.y = u1;
    *reinterpret_cast<uint2*>(&xb[(size_t)r * 832 + c4]) = u;
}

// W[K][N] fp32 -> Wt[NP][KP] bf16 transposed, zero-padded
__global__ __launch_bounds__(256)
void conv_w_k(const float* __restrict__ W, unsigned short* __restrict__ Wt,
              int K, int N, int KP, int NP)
{
    int idx = blockIdx.x * 256 + threadIdx.x;
    if (idx >= NP * KP) return;
    int n = idx / KP, k = idx - n * KP;
    float v = (n < N && k < K) ? W[(size_t)k * N + n] : 0.f;
    Wt[idx] = bf16_(v);
}

// h3[B,20] -> zb (decoder input, padded 64), fb ([z^2, z] padded 64), log_qz
__global__ __launch_bounds__(256)
void reparam_k(const float* __restrict__ h3, const float* __restrict__ eps,
               unsigned short* __restrict__ zb, unsigned short* __restrict__ fb,
               float* __restrict__ lqz)
{
    int r = blockIdx.x * blockDim.x + threadIdx.x;
    if (r >= BB) return;
    float acc = 0.f;
    #pragma unroll
    for (int j = 0; j < ZD; ++j) {
        float qm = h3[r * 2 * ZD + j];
        float qh = h3[r * 2 * ZD + ZD + j];
        float qv = sp_(qh) + 1e-8f;
        float e = eps[r * ZD + j];
        float zj = qm + sqrtf(qv) * e;
        zb[r * 64 + j] = bf16_(zj);
        fb[r * 64 + j] = bf16_(zj * zj);
        fb[r * 64 + ZD + j] = bf16_(zj);
        float d = zj - qm;
        acc += logf(6.283185307179586f * qv) + d * d / qv;
    }
    #pragma unroll
    for (int j = ZD; j < 64; ++j) zb[r * 64 + j] = 0;
    #pragma unroll
    for (int j = 2 * ZD; j < 64; ++j) fb[r * 64 + j] = 0;
    lqz[r] = -0.5f * acc;
}

// GMM prior -> G bf16 [2048][64] = [-0.5/v, m/v, pad]; cbias fp32 [2048] = c_k
__global__ __launch_bounds__(256)
void coef_k(const float* __restrict__ zpre, unsigned short* __restrict__ G,
            float* __restrict__ cbias)
{
    int k = blockIdx.x * blockDim.x + threadIdx.x;
    if (k >= 2048) return;
    if (k < KK) {
        float csum = 0.f;
        #pragma unroll
        for (int j = 0; j < ZD; ++j) {
            float m = zpre[k * ZD + j];
            float h = zpre[(KK + k) * ZD + j];
            float v = sp_(h) + 1e-8f;
            G[k * 64 + j] = bf16_(-0.5f / v);
            G[k * 64 + ZD + j] = bf16_(m / v);
            csum += logf(6.283185307179586f * v) + m * m / v;
        }
        #pragma unroll
        for (int j = 2 * ZD; j < 64; ++j) G[k * 64 + j] = 0;
        cbias[k] = -0.5f * csum;
    } else {
        #pragma unroll
        for (int j = 0; j < 64; ++j) G[k * 64 + j] = 0;
        cbias[k] = -1e30f;
    }
}

// stage-1 reduce: per-row lpz/kl/lpx, then block partial sums -> part[32][3]
__global__ __launch_bounds__(256)
void row_k(const float* __restrict__ pm, const float* __restrict__ ps,
           const float* __restrict__ lqz, const float* __restrict__ lpx_part,
           float* __restrict__ part)
{
    int r = blockIdx.x * 256 + threadIdx.x;
    float M = -1e30f;
    #pragma unroll
    for (int i = 0; i < NSP; ++i) M = fmaxf(M, pm[(size_t)i * BB + r]);
    float S = 0.f;
    #pragma unroll
    for (int i = 0; i < NSP; ++i) S += ps[(size_t)i * BB + r] * expf(pm[(size_t)i * BB + r] - M);
    float lpz = M + logf(S) - 7.6009024595420824f;  // log(2000)
    float lp = 0.f;
    #pragma unroll
    for (int t = 0; t < 13; ++t) lp += lpx_part[(size_t)t * BB + r];
    float kl = lqz[r] - lpz;
    float ne = kl - lp, re = -lp;
    #pragma unroll
    for (int d = 1; d < 64; d <<= 1) {
        ne += __shfl_xor(ne, d);
        kl += __shfl_xor(kl, d);
        re += __shfl_xor(re, d);
    }
    __shared__ float sm[4][3];
    int l = threadIdx.x & 63, w = threadIdx.x >> 6;
    if (l == 0) { sm[w][0] = ne; sm[w][1] = kl; sm[w][2] = re; }
    __syncthreads();
    if (threadIdx.x == 0) {
        part[blockIdx.x * 3 + 0] = sm[0][0] + sm[1][0] + sm[2][0] + sm[3][0];
        part[blockIdx.x * 3 + 1] = sm[0][1] + sm[1][1] + sm[2][1] + sm[3][1];
        part[blockIdx.x * 3 + 2] = sm[0][2] + sm[1][2] + sm[2][2] + sm[3][2];
    }
}

__global__ void fin_k(const float* __restrict__ part, float* __restrict__ out)
{
    int t = threadIdx.x;   // 0..2
    if (t < 3) {
        float s = 0.f;
        for (int b = 0; b < 32; ++b) s += part[b * 3 + t];
        out[t] = s / (float)BB;
    }
}

extern "C" void kernel_launch(void* const* d_in, const int* in_sizes, int n_in,
                              void* d_out, int out_size, void* d_ws, size_t ws_size,
                              hipStream_t stream)
{
    const float* x    = (const float*)d_in[0];
    const float* eps  = (const float*)d_in[1];
    const float* zpre = (const float*)d_in[2];
    const float* ew1  = (const float*)d_in[3];
    const float* eb1  = (const float*)d_in[4];
    const float* ew2  = (const float*)d_in[5];
    const float* eb2  = (const float*)d_in[6];
    const float* ew3  = (const float*)d_in[7];
    const float* eb3  = (const float*)d_in[8];
    const float* dw1  = (const float*)d_in[9];
    const float* db1  = (const float*)d_in[10];
    const float* dw2  = (const float*)d_in[11];
    const float* db2  = (const float*)d_in[12];
    const float* dw3  = (const float*)d_in[13];
    const float* db3  = (const float*)d_in[14];
    float* out = (float*)d_out;

    float* ws    = (float*)d_ws;
    float* h3    = ws;                            // BB*20
    float* lqz   = h3 + (size_t)BB * 2 * ZD;      // BB
    float* lpx   = lqz + BB;                      // 13*BB
    float* cbias = lpx + (size_t)13 * BB;         // 2048
    float* pm    = cbias + 2048;                  // 32*BB
    float* ps    = pm + (size_t)NSP * BB;         // 32*BB
    float* part  = ps + (size_t)NSP * BB;         // 96

    unsigned short* ub = (unsigned short*)(part + 96);
    unsigned short* xb  = ub; ub += (size_t)BB * 832;
    unsigned short* h1b = ub; ub += (size_t)BB * 320;
    unsigned short* h2b = ub; ub += (size_t)BB * 320;
    unsigned short* zb  = ub; ub += (size_t)BB * 64;
    unsigned short* fb  = ub; ub += (size_t)BB * 64;
    unsigned short* w1t = ub; ub += 320 * 832;
    unsigned short* w2t = ub; ub += 320 * 320;
    unsigned short* w3t = ub; ub += 64 * 320;
    unsigned short* d1t = ub; ub += 320 * 64;
    unsigned short* d2t = ub; ub += 320 * 320;
    unsigned short* d3t = ub; ub += 832 * 320;
    unsigned short* G   = ub; ub += 2048 * 64;

    dim3 blk(256);

    conv_x_k<<<(BB * 208) / 256, blk, 0, stream>>>(x, xb);
    conv_w_k<<<(320 * 832 + 255) / 256, blk, 0, stream>>>(ew1, w1t, XD, HH, 832, 320);
    conv_w_k<<<(320 * 320 + 255) / 256, blk, 0, stream>>>(ew2, w2t, HH, HH, 320, 320);
    conv_w_k<<<(64 * 320 + 255) / 256, blk, 0, stream>>>(ew3, w3t, HH, 2 * ZD, 320, 64);
    conv_w_k<<<(320 * 64 + 255) / 256, blk, 0, stream>>>(dw1, d1t, ZD, HH, 64, 320);
    conv_w_k<<<(320 * 320 + 255) / 256, blk, 0, stream>>>(dw2, d2t, HH, HH, 320, 320);
    conv_w_k<<<(832 * 320 + 255) / 256, blk, 0, stream>>>(dw3, d3t, HH, XD, 320, 832);
    coef_k<<<2048 / 256, blk, 0, stream>>>(zpre, G, cbias);

    // encoder
    mgemm<1><<<dim3(5, 128), blk, 0, stream>>>(xb, w1t, eb1, h1b, nullptr, nullptr, nullptr, 832, HH, 320);
    mgemm<1><<<dim3(5, 128), blk, 0, stream>>>(h1b, w2t, eb2, h2b, nullptr, nullptr, nullptr, 320, HH, 320);
    mgemm<0><<<dim3(1, 128), blk, 0, stream>>>(h2b, w3t, eb3, nullptr, h3, nullptr, nullptr, 320, 2 * ZD, 0);
    reparam_k<<<BB / 256, blk, 0, stream>>>(h3, eps, zb, fb, lqz);
    // decoder
    mgemm<1><<<dim3(5, 128), blk, 0, stream>>>(zb, d1t, db1, h1b, nullptr, nullptr, nullptr, 64, HH, 320);
    mgemm<1><<<dim3(5, 128), blk, 0, stream>>>(h1b, d2t, db2, h2b, nullptr, nullptr, nullptr, 320, HH, 320);
    mgemm<2><<<dim3(13, 128), blk, 0, stream>>>(h2b, d3t, db3, nullptr, nullptr, x, lpx, 320, XD, 0);
    // GMM prior: comp = F @ G^T + c_k, fused logsumexp per 64-col tile
    mgemm<3><<<dim3(NSP, 128), blk, 0, stream>>>(fb, G, cbias, nullptr, pm, nullptr, ps, 64, 2048, 0);
    // finalize
    row_k<<<32, blk, 0, stream>>>(pm, ps, lqz, lpx, part);
    fin_k<<<1, 64, 0, stream>>>(part, out);
}

// Round 5
// 159.917 us; speedup vs baseline: 3.3597x; 1.1341x over previous
//
#include <hip/hip_runtime.h>
#include <hip/hip_bf16.h>
#include <math.h>

#define BB 8192
#define XD 784
#define ZD 10
#define KK 2000
#define HH 300
#define NSP 32          // column tiles of the comp GEMM (2048/64)

typedef short short8 __attribute__((ext_vector_type(8)));
typedef float f32x4 __attribute__((ext_vector_type(4)));

// fast-math variants: v_exp_f32 / v_log_f32 (rel err ~1e-6, threshold is 1e1)
__device__ __forceinline__ float sp_(float x) {
    return fmaxf(x, 0.f) + __logf(1.f + __expf(-fabsf(x)));
}
__device__ __forceinline__ float elu_(float x) { return x > 0.f ? x : __expf(x) - 1.f; }
__device__ __forceinline__ unsigned short bf16_(float v) {
    __hip_bfloat16 h = __float2bfloat16(v);
    return __builtin_bit_cast(unsigned short, h);
}
__device__ __forceinline__ float b2f_(unsigned short u) {
    return __builtin_bit_cast(float, (unsigned int)u << 16);
}

__device__ __forceinline__ void gl16(const unsigned short* g, unsigned short* l) {
    __builtin_amdgcn_global_load_lds(
        (const __attribute__((address_space(1))) unsigned int*)g,
        (__attribute__((address_space(3))) unsigned int*)l, 16, 0, 0);
}

// ---------------------------------------------------------------------------
// bf16 MFMA GEMM body: C[M,N] = act(A[M,KP] @ Wt[N,KP]^T + bias)
// BM=64, BN=64, BK=64; 4 waves (2x2), each 32x32 = 2x2 frags of 16x16x32.
// 3-deep LDS pipeline, counted vmcnt(8/4/0) (never drain mid-pipe), raw
// s_barrier. LDS fragment-major: 1024B group = 16 rows x 32 k; staging is
// linear (global_load_lds-compatible); ds_read_b128 contiguous, 0 conflicts.
// XCD-chunked swizzle: hardware round-robins linear block id across 8 XCDs;
// id&7 selects an m-slab of MT/8 m-tiles so each XCD's A working set stays
// L2-resident across all its n-tiles. Requires gridDim.y % 8 == 0.
// MODE 0: store fp32 (c<N). MODE 1: store bf16 elu (stride NST, zero-pad).
// MODE 2: fused sum_c(Xb*logit - softplus(logit)) -> lpx[ntile][row],
//         Xb = bf16 x (stride XST).
// MODE 3: per-row logsumexp over 64-col tile -> pm (Cf), ps (lpx);
//         bias = c_k fp32, padded cols bias=-1e30.
// KP: multiple of 64, passed as a literal -> loop fully unrolled per layer.
// ---------------------------------------------------------------------------
template<int MODE>
__device__ __forceinline__ void mgemm_body(
    const unsigned short* __restrict__ Ab, const unsigned short* __restrict__ Wt,
    const float* __restrict__ bias, unsigned short* __restrict__ Cb,
    float* __restrict__ Cf, const unsigned short* __restrict__ Xb,
    float* __restrict__ lpx, int KP, int N, int NST, int XST)
{
    __shared__ __align__(16) unsigned short lds[3][8192];
    __shared__ float redm[64][2];
    __shared__ float reds[64][2];
    const int tid = threadIdx.x;
    const int w = tid >> 6, l = tid & 63;
    const int wr = w >> 1, wc = w & 1;

    // XCD-chunked swizzle (bijective: grid = NX * MT, MT % 8 == 0)
    const int NX = gridDim.x, MT = gridDim.y;
    const int id = blockIdx.x + NX * blockIdx.y;
    const int msl = MT >> 3;
    const int r8 = id >> 3;
    const int mt = (id & 7) * msl + (r8 % msl);
    const int ntl = r8 / msl;
    const int m0 = mt * 64, n0 = ntl * 64;

    const int rg = l & 15;          // row within 16-row group
    const int kg = (l >> 4) * 8;    // k-offset within 32-k half

    const unsigned short* gA0 = Ab + (size_t)(m0 + w * 16 + rg) * KP + kg;
    const unsigned short* gA1 = gA0 + 32;
    const unsigned short* gB0 = Wt + (size_t)(n0 + w * 16 + rg) * KP + kg;
    const unsigned short* gB1 = gB0 + 32;

#define STAGE(b, tk) do { \
        unsigned short* Lb = &lds[b][0]; \
        const int kb_ = (tk) << 6; \
        gl16(gA0 + kb_, Lb + (2 * w + 0) * 512); \
        gl16(gA1 + kb_, Lb + (2 * w + 1) * 512); \
        gl16(gB0 + kb_, Lb + 4096 + (2 * w + 0) * 512); \
        gl16(gB1 + kb_, Lb + 4096 + (2 * w + 1) * 512); \
    } while (0)

    f32x4 acc[2][2];
    #pragma unroll
    for (int i = 0; i < 2; ++i)
        #pragma unroll
        for (int j = 0; j < 2; ++j)
            acc[i][j] = (f32x4){0.f, 0.f, 0.f, 0.f};

    const int nt = KP >> 6;
    STAGE(0, 0);
    if (nt > 1) STAGE(1, 1);
    int cur = 0, pf = 2;
    #pragma unroll
    for (int t = 0; t < nt; ++t) {
        if (t + 2 < nt) STAGE(pf, t + 2);
        const int rem = nt - 1 - t;   // tiles still in flight beyond t
        if (rem >= 2)      asm volatile("s_waitcnt vmcnt(8)" ::: "memory");
        else if (rem == 1) asm volatile("s_waitcnt vmcnt(4)" ::: "memory");
        else               asm volatile("s_waitcnt vmcnt(0)" ::: "memory");
        __builtin_amdgcn_s_barrier();          // tile t visible to all waves
        __builtin_amdgcn_sched_barrier(0);
        const unsigned short* L = &lds[cur][0];
        short8 af[2][2], bv[2][2];
        #pragma unroll
        for (int mf = 0; mf < 2; ++mf)
            #pragma unroll
            for (int s = 0; s < 2; ++s)
                af[mf][s] = *reinterpret_cast<const short8*>(
                    &L[((wr * 2 + mf) * 2 + s) * 512 + l * 8]);
        #pragma unroll
        for (int nf = 0; nf < 2; ++nf)
            #pragma unroll
            for (int s = 0; s < 2; ++s)
                bv[nf][s] = *reinterpret_cast<const short8*>(
                    &L[4096 + ((wc * 2 + nf) * 2 + s) * 512 + l * 8]);
        #pragma unroll
        for (int mf = 0; mf < 2; ++mf)
            #pragma unroll
            for (int nf = 0; nf < 2; ++nf) {
                acc[mf][nf] = __builtin_amdgcn_mfma_f32_16x16x32_bf16(af[mf][0], bv[nf][0], acc[mf][nf], 0, 0, 0);
                acc[mf][nf] = __builtin_amdgcn_mfma_f32_16x16x32_bf16(af[mf][1], bv[nf][1], acc[mf][nf], 0, 0, 0);
            }
        asm volatile("s_waitcnt lgkmcnt(0)" ::: "memory");  // reads of buf done
        __builtin_amdgcn_sched_barrier(0);
        __builtin_amdgcn_s_barrier();          // buf[cur] free for re-stage
        __builtin_amdgcn_sched_barrier(0);
        cur = (cur + 1 < 3) ? cur + 1 : 0;
        pf  = (pf + 1 < 3) ? pf + 1 : 0;
    }
#undef STAGE

    const int cl = l & 15;
    const int g4 = (l >> 4) * 4;
    if (MODE == 3) {
        const float b0 = bias[n0 + wc * 32 + cl];
        const float b1 = bias[n0 + wc * 32 + 16 + cl];
        #pragma unroll
        for (int mf = 0; mf < 2; ++mf) {
            #pragma unroll
            for (int r = 0; r < 4; ++r) {
                float v0 = acc[mf][0][r] + b0;
                float v1 = acc[mf][1][r] + b1;
                float mx = fmaxf(v0, v1);
                mx = fmaxf(mx, __shfl_xor(mx, 1));
                mx = fmaxf(mx, __shfl_xor(mx, 2));
                mx = fmaxf(mx, __shfl_xor(mx, 4));
                mx = fmaxf(mx, __shfl_xor(mx, 8));
                float s = __expf(v0 - mx) + __expf(v1 - mx);
                s += __shfl_xor(s, 1); s += __shfl_xor(s, 2);
                s += __shfl_xor(s, 4); s += __shfl_xor(s, 8);
                if (cl == 0) {
                    int rl = wr * 32 + mf * 16 + g4 + r;
                    redm[rl][wc] = mx;
                    reds[rl][wc] = s;
                }
            }
        }
        __syncthreads();
        if (tid < 64) {
            float mA = redm[tid][0], mB = redm[tid][1];
            float M = fmaxf(mA, mB);
            float S = reds[tid][0] * __expf(mA - M) + reds[tid][1] * __expf(mB - M);
            Cf[(size_t)ntl * BB + m0 + tid] = M;    // pm
            lpx[(size_t)ntl * BB + m0 + tid] = S;   // ps
        }
    } else if (MODE == 2) {
        #pragma unroll
        for (int mf = 0; mf < 2; ++mf) {
            #pragma unroll
            for (int r = 0; r < 4; ++r) {
                const int row = m0 + wr * 32 + mf * 16 + g4 + r;
                float s = 0.f;
                #pragma unroll
                for (int nf = 0; nf < 2; ++nf) {
                    const int c = n0 + wc * 32 + nf * 16 + cl;
                    if (c < N) {
                        float lv = acc[mf][nf][r] + bias[c];
                        float xv = b2f_(Xb[(size_t)row * XST + c]);
                        s += xv * lv - sp_(lv);
                    }
                }
                s += __shfl_xor(s, 1); s += __shfl_xor(s, 2);
                s += __shfl_xor(s, 4); s += __shfl_xor(s, 8);
                if (cl == 0) redm[wr * 32 + mf * 16 + g4 + r][wc] = s;
            }
        }
        __syncthreads();
        if (tid < 64)
            lpx[(size_t)ntl * BB + m0 + tid] = redm[tid][0] + redm[tid][1];
    } else {
        #pragma unroll
        for (int mf = 0; mf < 2; ++mf) {
            #pragma unroll
            for (int r = 0; r < 4; ++r) {
                const int row = m0 + wr * 32 + mf * 16 + g4 + r;
                #pragma unroll
                for (int nf = 0; nf < 2; ++nf) {
                    const int c = n0 + wc * 32 + nf * 16 + cl;
                    float bvl = (c < N) ? bias[c] : 0.f;
                    float v = acc[mf][nf][r] + bvl;
                    if (MODE == 0) {
                        if (c < N) Cf[(size_t)row * N + c] = v;
                    } else {
                        float o = (c < N) ? elu_(v) : 0.f;
                        if (c < NST) Cb[(size_t)row * NST + c] = bf16_(o);
                    }
                }
            }
        }
    }
}

// named wrappers: per-layer profiler visibility + compile-time KP
__global__ __launch_bounds__(256) void k_enc1(const unsigned short* A, const unsigned short* W,
                                              const float* b, unsigned short* C) {
    mgemm_body<1>(A, W, b, C, nullptr, nullptr, nullptr, 832, HH, 320, 0);
}
__global__ __launch_bounds__(256) void k_enc2(const unsigned short* A, const unsigned short* W,
                                              const float* b, unsigned short* C) {
    mgemm_body<1>(A, W, b, C, nullptr, nullptr, nullptr, 320, HH, 320, 0);
}
__global__ __launch_bounds__(256) void k_enc3(const unsigned short* A, const unsigned short* W,
                                              const float* b, float* C) {
    mgemm_body<0>(A, W, b, nullptr, C, nullptr, nullptr, 320, 2 * ZD, 0, 0);
}
__global__ __launch_bounds__(256) void k_dec1(const unsigned short* A, const unsigned short* W,
                                              const float* b, unsigned short* C) {
    mgemm_body<1>(A, W, b, C, nullptr, nullptr, nullptr, 64, HH, 320, 0);
}
__global__ __launch_bounds__(256) void k_dec2(const unsigned short* A, const unsigned short* W,
                                              const float* b, unsigned short* C) {
    mgemm_body<1>(A, W, b, C, nullptr, nullptr, nullptr, 320, HH, 320, 0);
}
__global__ __launch_bounds__(256) void k_dec3(const unsigned short* A, const unsigned short* W,
                                              const float* b, const unsigned short* Xb, float* lpx) {
    mgemm_body<2>(A, W, b, nullptr, nullptr, Xb, lpx, 320, XD, 0, 832);
}
__global__ __launch_bounds__(256) void k_comp(const unsigned short* A, const unsigned short* W,
                                              const float* b, float* pm, float* ps) {
    mgemm_body<3>(A, W, b, nullptr, pm, nullptr, ps, 64, 2048, 0, 0);
}

// x[8192][784] fp32 -> xb[8192][832] bf16 zero-padded
__global__ __launch_bounds__(256)
void conv_x_k(const float* __restrict__ x, unsigned short* __restrict__ xb)
{
    int idx = blockIdx.x * 256 + threadIdx.x;
    int r = idx / 208, c4 = (idx - r * 208) * 4;
    if (r >= BB) return;
    unsigned int u0 = 0, u1 = 0;
    if (c4 < XD) {
        float4 v = *reinterpret_cast<const float4*>(&x[(size_t)r * XD + c4]);
        u0 = (unsigned)bf16_(v.x) | ((unsigned)bf16_(v.y) << 16);
        u1 = (unsigned)bf16_(v.z) | ((unsigned)bf16_(v.w) << 16);
    }
    uint2 u; u.x = u0; u.y = u1;
    *reinterpret_cast<uint2*>(&xb[(size_t)r * 832 + c4]) = u;
}

// W[K][N] fp32 -> Wt[NP][KP] bf16 transposed, zero-padded
__global__ __launch_bounds__(256)
void conv_w_k(const float* __restrict__ W, unsigned short* __restrict__ Wt,
              int K, int N, int KP, int NP)
{
    int idx = blockIdx.x * 256 + threadIdx.x;
    if (idx >= NP * KP) return;
    int n = idx / KP, k = idx - n * KP;
    float v = (n < N && k < K) ? W[(size_t)k * N + n] : 0.f;
    Wt[idx] = bf16_(v);
}

// h3[B,20] -> zb (decoder input, padded 64), fb ([z^2, z] padded 64), log_qz
__global__ __launch_bounds__(256)
void reparam_k(const float* __restrict__ h3, const float* __restrict__ eps,
               unsigned short* __restrict__ zb, unsigned short* __restrict__ fb,
               float* __restrict__ lqz)
{
    int r = blockIdx.x * blockDim.x + threadIdx.x;
    if (r >= BB) return;
    float acc = 0.f;
    #pragma unroll
    for (int j = 0; j < ZD; ++j) {
        float qm = h3[r * 2 * ZD + j];
        float qh = h3[r * 2 * ZD + ZD + j];
        float qv = sp_(qh) + 1e-8f;
        float e = eps[r * ZD + j];
        float zj = qm + sqrtf(qv) * e;
        zb[r * 64 + j] = bf16_(zj);
        fb[r * 64 + j] = bf16_(zj * zj);
        fb[r * 64 + ZD + j] = bf16_(zj);
        float d = zj - qm;
        acc += __logf(6.283185307179586f * qv) + d * d / qv;
    }
    #pragma unroll
    for (int j = ZD; j < 64; ++j) zb[r * 64 + j] = 0;
    #pragma unroll
    for (int j = 2 * ZD; j < 64; ++j) fb[r * 64 + j] = 0;
    lqz[r] = -0.5f * acc;
}

// GMM prior -> G bf16 [2048][64] = [-0.5/v, m/v, pad]; cbias fp32 = c_k
__global__ __launch_bounds__(256)
void coef_k(const float* __restrict__ zpre, unsigned short* __restrict__ G,
            float* __restrict__ cbias)
{
    int k = blockIdx.x * blockDim.x + threadIdx.x;
    if (k >= 2048) return;
    if (k < KK) {
        float csum = 0.f;
        #pragma unroll
        for (int j = 0; j < ZD; ++j) {
            float m = zpre[k * ZD + j];
            float h = zpre[(KK + k) * ZD + j];
            float v = sp_(h) + 1e-8f;
            G[k * 64 + j] = bf16_(-0.5f / v);
            G[k * 64 + ZD + j] = bf16_(m / v);
            csum += __logf(6.283185307179586f * v) + m * m / v;
        }
        #pragma unroll
        for (int j = 2 * ZD; j < 64; ++j) G[k * 64 + j] = 0;
        cbias[k] = -0.5f * csum;
    } else {
        #pragma unroll
        for (int j = 0; j < 64; ++j) G[k * 64 + j] = 0;
        cbias[k] = -1e30f;
    }
}

// stage-1 reduce: per-row lpz/kl/lpx, then block partial sums -> part[32][3]
__global__ __launch_bounds__(256)
void row_k(const float* __restrict__ pm, const float* __restrict__ ps,
           const float* __restrict__ lqz, const float* __restrict__ lpx_part,
           float* __restrict__ part)
{
    int r = blockIdx.x * 256 + threadIdx.x;
    float M = -1e30f;
    #pragma unroll
    for (int i = 0; i < NSP; ++i) M = fmaxf(M, pm[(size_t)i * BB + r]);
    float S = 0.f;
    #pragma unroll
    for (int i = 0; i < NSP; ++i) S += ps[(size_t)i * BB + r] * __expf(pm[(size_t)i * BB + r] - M);
    float lpz = M + __logf(S) - 7.6009024595420824f;  // log(2000)
    float lp = 0.f;
    #pragma unroll
    for (int t = 0; t < 13; ++t) lp += lpx_part[(size_t)t * BB + r];
    float kl = lqz[r] - lpz;
    float ne = kl - lp, re = -lp;
    #pragma unroll
    for (int d = 1; d < 64; d <<= 1) {
        ne += __shfl_xor(ne, d);
        kl += __shfl_xor(kl, d);
        re += __shfl_xor(re, d);
    }
    __shared__ float sm[4][3];
    int l = threadIdx.x & 63, w = threadIdx.x >> 6;
    if (l == 0) { sm[w][0] = ne; sm[w][1] = kl; sm[w][2] = re; }
    __syncthreads();
    if (threadIdx.x == 0) {
        part[blockIdx.x * 3 + 0] = sm[0][0] + sm[1][0] + sm[2][0] + sm[3][0];
        part[blockIdx.x * 3 + 1] = sm[0][1] + sm[1][1] + sm[2][1] + sm[3][1];
        part[blockIdx.x * 3 + 2] = sm[0][2] + sm[1][2] + sm[2][2] + sm[3][2];
    }
}

__global__ void fin_k(const float* __restrict__ part, float* __restrict__ out)
{
    int t = threadIdx.x;   // 0..2
    if (t < 3) {
        float s = 0.f;
        for (int b = 0; b < 32; ++b) s += part[b * 3 + t];
        out[t] = s / (float)BB;
    }
}

extern "C" void kernel_launch(void* const* d_in, const int* in_sizes, int n_in,
                              void* d_out, int out_size, void* d_ws, size_t ws_size,
                              hipStream_t stream)
{
    const float* x    = (const float*)d_in[0];
    const float* eps  = (const float*)d_in[1];
    const float* zpre = (const float*)d_in[2];
    const float* ew1  = (const float*)d_in[3];
    const float* eb1  = (const float*)d_in[4];
    const float* ew2  = (const float*)d_in[5];
    const float* eb2  = (const float*)d_in[6];
    const float* ew3  = (const float*)d_in[7];
    const float* eb3  = (const float*)d_in[8];
    const float* dw1  = (const float*)d_in[9];
    const float* db1  = (const float*)d_in[10];
    const float* dw2  = (const float*)d_in[11];
    const float* db2  = (const float*)d_in[12];
    const float* dw3  = (const float*)d_in[13];
    const float* db3  = (const float*)d_in[14];
    float* out = (float*)d_out;

    float* ws    = (float*)d_ws;
    float* h3    = ws;                            // BB*20
    float* lqz   = h3 + (size_t)BB * 2 * ZD;      // BB
    float* lpx   = lqz + BB;                      // 13*BB
    float* cbias = lpx + (size_t)13 * BB;         // 2048
    float* pm    = cbias + 2048;                  // 32*BB
    float* ps    = pm + (size_t)NSP * BB;         // 32*BB
    float* part  = ps + (size_t)NSP * BB;         // 96

    unsigned short* ub = (unsigned short*)(part + 96);
    unsigned short* xb  = ub; ub += (size_t)BB * 832;
    unsigned short* h1b = ub; ub += (size_t)BB * 320;
    unsigned short* h2b = ub; ub += (size_t)BB * 320;
    unsigned short* zb  = ub; ub += (size_t)BB * 64;
    unsigned short* fb  = ub; ub += (size_t)BB * 64;
    unsigned short* w1t = ub; ub += 320 * 832;
    unsigned short* w2t = ub; ub += 320 * 320;
    unsigned short* w3t = ub; ub += 64 * 320;
    unsigned short* d1t = ub; ub += 320 * 64;
    unsigned short* d2t = ub; ub += 320 * 320;
    unsigned short* d3t = ub; ub += 832 * 320;
    unsigned short* G   = ub; ub += 2048 * 64;

    dim3 blk(256);

    conv_x_k<<<(BB * 208) / 256, blk, 0, stream>>>(x, xb);
    conv_w_k<<<(320 * 832 + 255) / 256, blk, 0, stream>>>(ew1, w1t, XD, HH, 832, 320);
    conv_w_k<<<(320 * 320 + 255) / 256, blk, 0, stream>>>(ew2, w2t, HH, HH, 320, 320);
    conv_w_k<<<(64 * 320 + 255) / 256, blk, 0, stream>>>(ew3, w3t, HH, 2 * ZD, 320, 64);
    conv_w_k<<<(320 * 64 + 255) / 256, blk, 0, stream>>>(dw1, d1t, ZD, HH, 64, 320);
    conv_w_k<<<(320 * 320 + 255) / 256, blk, 0, stream>>>(dw2, d2t, HH, HH, 320, 320);
    conv_w_k<<<(832 * 320 + 255) / 256, blk, 0, stream>>>(dw3, d3t, HH, XD, 320, 832);
    coef_k<<<2048 / 256, blk, 0, stream>>>(zpre, G, cbias);

    // encoder
    k_enc1<<<dim3(5, 128), blk, 0, stream>>>(xb, w1t, eb1, h1b);
    k_enc2<<<dim3(5, 128), blk, 0, stream>>>(h1b, w2t, eb2, h2b);
    k_enc3<<<dim3(1, 128), blk, 0, stream>>>(h2b, w3t, eb3, h3);
    reparam_k<<<BB / 256, blk, 0, stream>>>(h3, eps, zb, fb, lqz);
    // decoder
    k_dec1<<<dim3(5, 128), blk, 0, stream>>>(zb, d1t, db1, h1b);
    k_dec2<<<dim3(5, 128), blk, 0, stream>>>(h1b, d2t, db2, h2b);
    k_dec3<<<dim3(13, 128), blk, 0, stream>>>(h2b, d3t, db3, xb, lpx);
    // GMM prior: comp = F @ G^T + c_k, fused logsumexp per 64-col tile
    k_comp<<<dim3(NSP, 128), blk, 0, stream>>>(fb, G, cbias, pm, ps);
    // finalize
    row_k<<<32, blk, 0, stream>>>(pm, ps, lqz, lpx, part);
    fin_k<<<1, 64, 0, stream>>>(part, out);
}